// Round 1
// baseline (238.284 us; speedup 1.0000x reference)
//
#include <hip/hip_runtime.h>
#include <hip/hip_bf16.h>
#include <math.h>

#define BB 32
#define SS 2048
#define HE 1024
#define HD 1024
#define WROW (HE + HD)   // 2048

typedef __attribute__((ext_vector_type(8))) short bf16x8;
typedef __attribute__((ext_vector_type(4))) float f32x4;
typedef __attribute__((ext_vector_type(8))) unsigned short u16x8;

__device__ __forceinline__ unsigned short f2bf(float f) {
    union { float f; unsigned u; } v; v.f = f;
    unsigned r = v.u + 0x7fffu + ((v.u >> 16) & 1u);   // RNE
    return (unsigned short)(r >> 16);
}

__device__ __forceinline__ unsigned int pk2(float x, float y) {
    union { __hip_bfloat162 h; unsigned int u; } c;
    c.h = __float22bfloat162_rn(float2{x, y});          // v_cvt_pk_bf16_f32
    return c.u;
}

#define LGKM0()  asm volatile("s_waitcnt lgkmcnt(0)" ::: "memory")
#define BAR()    asm volatile("s_barrier" ::: "memory")

// ---------------- cvt: W_enc fp32 -> bf16 fragment-major ----------------
// Record (g, ksg): 64 lanes x 16B; lane l = W[d=g*16+(l&15)][k=ksg*32+(l>>4)*8 ..+8]
// g = d>>4 (0..63), ksg = k>>5 (0..31). One wave's bg load = 1KB contiguous.
__global__ __launch_bounds__(256) void k_cvt_wfrag(const float* __restrict__ W,
                                                   unsigned short* __restrict__ wf) {
    int i = blockIdx.x * 256 + threadIdx.x;   // 0..131071 (8-elem chunks)
    int d = i >> 7;                            // 0..1023
    int c = i & 127;                           // k-chunk: k = c*8
    const float4* src = (const float4*)(W + (size_t)d * WROW + c * 8);
    float4 a = src[0], b2 = src[1];
    u16x8 o;
    o[0] = f2bf(a.x);  o[1] = f2bf(a.y);  o[2] = f2bf(a.z);  o[3] = f2bf(a.w);
    o[4] = f2bf(b2.x); o[5] = f2bf(b2.y); o[6] = f2bf(b2.z); o[7] = f2bf(b2.w);
    int ksg = c >> 2, hi = c & 3;
    int l   = (d & 15) + 16 * hi;
    int g   = d >> 4;
    *(u16x8*)(wf + ((size_t)(g * 32 + ksg) * 64 + l) * 8) = o;
}

// ---------------- proj_dec: W_dec read ONCE total ----------------
__global__ __launch_bounds__(256) void k_projdec2(const float* __restrict__ dec,
                                                  const float* __restrict__ W,
                                                  float* __restrict__ proj) {
    const int tid = threadIdx.x;
    const int dl = tid >> 6;
    const int b  = (tid >> 1) & 31;
    const int hf = tid & 1;
    const int d  = blockIdx.x * 4 + dl;
    const float* wrow = W + (size_t)d * WROW + HE + hf * 512;
    const float* dv   = dec + b * HD + hf * 512;
    float s = 0.f;
    #pragma unroll 4
    for (int e = 0; e < 512; e += 4) {
        float4 w4 = *(const float4*)(wrow + e);
        float4 x4 = *(const float4*)(dv + e);
        s += w4.x * x4.x + w4.y * x4.y + w4.z * x4.z + w4.w * x4.w;
    }
    s += __shfl_xor(s, 1, 64);
    if (hf == 0) proj[b * HD + d] = s;
}

// ---------------- 8-wave 256x256 MFMA scores; B direct global->reg ----------------
// psc[nb][t] = sum_{d in nb*256..+256} V[d]*tanh(y[t][d]+proj[b][d])
// 8 waves 2Mx4N, wave-tile 128x64, acc 128 AGPR (256-reg budget, 2 waves/SIMD).
// A: reg-staged fp32->bf16 -> XOR-swizzled LDS dbuf (only LDS user).
// B: fragment-major global loads straight to VGPR (L2-resident 2MB), issued ~1
//    K-tile ahead; compiler emits exact counted vmcnt per use.
// NEW (this round): m201/m218 per-phase double-barrier schedule. 4 phases per
// K-tile, each {ds_read af; slot; s_barrier; lgkmcnt(0); setprio1; 16 MFMA;
// setprio0; s_barrier}. Forces all waves to cluster ds_read bursts vs MFMA
// bursts (anti-lockstep drift), keeps B loads in flight across barriers
// (counted vmcnt, never drain-0 in loop). Phase barriers subsume the A-dbuf
// coherence barrier. launch_bounds(512,2) pins the 256-reg budget.
__global__ __launch_bounds__(512, 2) void k_scores_mfma8b(
        const float* __restrict__ enc,             // [65536][1024] fp32
        const unsigned short* __restrict__ wf,     // fragment-major bf16 W_enc
        const float* __restrict__ V,
        const float* __restrict__ proj,            // [32][1024]
        float* __restrict__ psc) {                 // [4][65536]
    __shared__ unsigned short SM[32768];           // A dbuf: [2][16384] (256 rows x 64 k)

    const int tid = threadIdx.x;
    const int wv = tid >> 6, ln = tid & 63, l15 = ln & 15, lg = ln >> 4;
    const int wr = wv >> 2, wc = wv & 3;

    // T1: bijective XCD swizzle; 4 consecutive logical ids (same token-tile, 4 nb) per chunk
    const int lid  = (blockIdx.x & 7) * 128 + (blockIdx.x >> 3);
    const int trow = lid >> 2, nb = lid & 3;
    const int t0   = trow * 256;
    const int b    = t0 >> 11;

    f32x4 acc[8][4];
    #pragma unroll
    for (int m = 0; m < 8; m++)
        #pragma unroll
        for (int n = 0; n < 4; n++) acc[m][n] = (f32x4){0.f, 0.f, 0.f, 0.f};

    float4 areg[4][2];        // one K-tile of A: 256 rows x 64 k fp32, 8 float4/thread
    bf16x8 bg0[4], bg1[4];    // B fragments for ks0 / ks1 (consume-then-reload)

    #define LOAD_A(k) do { \
        _Pragma("unroll") \
        for (int p = 0; p < 4; p++) { \
            const float4* g_ = (const float4*)(enc + (size_t)(t0 + p * 64 + (tid >> 3)) * 1024 + (k) + (tid & 7) * 8); \
            areg[p][0] = g_[0]; areg[p][1] = g_[1]; \
        } } while (0)

    #define CVTW_A(buf) do { \
        _Pragma("unroll") \
        for (int p = 0; p < 4; p++) { \
            int row_ = p * 64 + (tid >> 3); \
            union { u16x8 s; uint4 u; } pk_; \
            pk_.u.x = pk2(areg[p][0].x, areg[p][0].y); \
            pk_.u.y = pk2(areg[p][0].z, areg[p][0].w); \
            pk_.u.z = pk2(areg[p][1].x, areg[p][1].y); \
            pk_.u.w = pk2(areg[p][1].z, areg[p][1].w); \
            *(u16x8*)&SM[(buf) * 16384 + row_ * 64 + (((tid & 7) ^ (row_ & 7)) << 3)] = pk_.s; \
        } } while (0)

    // bg fragment load: g = nb*16 + wc*4 + n, record (g*32 + t*2 + ksl), lane ln
    #define LOADB(bgx, tt, ksl) do { \
        _Pragma("unroll") \
        for (int n = 0; n < 4; n++) { \
            int g_ = nb * 16 + wc * 4 + n; \
            bgx[n] = *(const bf16x8*)(wf + ((size_t)(g_ * 32 + (tt) * 2 + (ksl)) * 64 + ln) * 8); \
        } } while (0)

    #define RD_A(af, Ac, mb, ks) do { \
        _Pragma("unroll") \
        for (int m = 0; m < 4; m++) { \
            int row_ = wr * 128 + (mb) + m * 16 + l15; \
            af[m] = *(const bf16x8*)&(Ac)[row_ * 64 + ((((ks) + lg) ^ (row_ & 7)) << 3)]; \
        } } while (0)

    #define MFMA44(mo, bg, af) do { \
        __builtin_amdgcn_s_setprio(1); \
        _Pragma("unroll") \
        for (int m = 0; m < 4; m++) \
            _Pragma("unroll") \
            for (int n = 0; n < 4; n++) \
                acc[(mo) + m][n] = __builtin_amdgcn_mfma_f32_16x16x32_bf16(af[m], bg[n], acc[(mo) + m][n], 0, 0, 0); \
        __builtin_amdgcn_s_setprio(0); } while (0)

    // ---- prologue: bg(0) both halves, A(0)->LDS, A(1) in flight ----
    LOADB(bg0, 0, 0); LOADB(bg1, 0, 1);
    LOAD_A(0);
    CVTW_A(0);                 // compiler waits A(0) loads, leaves bg in flight
    LOAD_A(64);                // A(1)
    LGKM0(); BAR();

    for (int t = 0; t < 16; ++t) {
        const int cur = t & 1, nxt = cur ^ 1;
        const unsigned short* Ac = SM + cur * 16384;
        bf16x8 af[4];

        // ---- phase 0: ks0, m0-3 ----
        RD_A(af, Ac, 0, 0);
        BAR(); LGKM0();
        MFMA44(0, bg0, af);
        BAR();

        // ---- phase 1: ks0, m4-7 ----
        RD_A(af, Ac, 64, 0);
        BAR(); LGKM0();
        MFMA44(4, bg0, af);
        BAR();

        // ---- phase 2: ks1, m0-3 ----
        // slot: bg0 dead after ph1 -> reload for t+1; convert A(t+1)->LDS nxt
        // (counted vmcnt on areg, A(t+2) loads issued after cvt reads areg);
        // writes drain at this phase's lgkmcnt(0).
        RD_A(af, Ac, 0, 4);
        if (t < 15) {
            LOADB(bg0, t + 1, 0);
            CVTW_A(nxt);
            if (t < 14) LOAD_A((t + 2) * 64);
        }
        BAR(); LGKM0();
        MFMA44(0, bg1, af);
        BAR();

        // ---- phase 3: ks1, m4-7 ----
        RD_A(af, Ac, 64, 4);
        BAR(); LGKM0();
        MFMA44(4, bg1, af);
        if (t < 15) LOADB(bg1, t + 1, 1);   // after last bg1 use; lands during t+1 ph0/ph1
        BAR();                               // also A-dbuf coherence for t+1
    }
    #undef LOAD_A
    #undef CVTW_A
    #undef LOADB
    #undef RD_A
    #undef MFMA44

    // ---- fused epilogue: sc[m][j] = sum_n V[d]*tanh(acc + proj) ----
    float sc[8][4];
    #pragma unroll
    for (int m = 0; m < 8; m++)
        #pragma unroll
        for (int j = 0; j < 4; j++) sc[m][j] = 0.f;
    #pragma unroll
    for (int n = 0; n < 4; n++) {
        int d = nb * 256 + wc * 64 + n * 16 + l15;
        float pd  = proj[b * 1024 + d];
        float vv  = V[d];
        float vv2 = 2.f * vv;
        #pragma unroll
        for (int m = 0; m < 8; m++)
            #pragma unroll
            for (int j = 0; j < 4; j++) {
                float y  = acc[m][n][j] + pd;
                float e2 = __expf(2.f * y);                 // saturates at +/-inf
                float r  = __builtin_amdgcn_rcpf(e2 + 1.f);
                sc[m][j] += vv - vv2 * r;                   // vv * tanh(y)
            }
    }

    __syncthreads();           // all waves done with LDS; safe to alias
    float* red = (float*)SM;   // 256 tokens x 64 cols, rotated = 64KB (exact fit)
    #pragma unroll
    for (int m = 0; m < 8; m++)
        #pragma unroll
        for (int j = 0; j < 4; j++) {
            int tok = wr * 128 + m * 16 + lg * 4 + j;
            int col = wc * 16 + l15;
            red[tok * 64 + ((col + tok) & 63)] = sc[m][j];
        }
    __syncthreads();
    if (tid < 256) {
        float s = 0.f;
        #pragma unroll
        for (int x = 0; x < 64; x++) s += red[tid * 64 + ((x + tid) & 63)];
        psc[nb * 65536 + t0 + tid] = s;
    }
}

// ---------------- masked softmax over S (sums 4 n-block partials) ----------------
__global__ __launch_bounds__(256) void k_softmax_p(const float* __restrict__ psc,
                                                   const int* __restrict__ mask,
                                                   float* __restrict__ attn) {
    __shared__ float sred[256];
    const int b = blockIdx.x, tid = threadIdx.x;
    float vals[8];
    int   msk[8];
    float lmax = -1e30f;
    #pragma unroll
    for (int i = 0; i < 8; i++) {
        int s = tid + i * 256;
        float v = 0.f;
        #pragma unroll
        for (int z = 0; z < 4; z++) v += psc[z * 65536 + b * SS + s];
        vals[i] = v;
        msk[i]  = mask[b * SS + s];
        if (!msk[i]) lmax = fmaxf(lmax, vals[i]);
    }
    sred[tid] = lmax; __syncthreads();
    for (int off = 128; off > 0; off >>= 1) {
        if (tid < off) sred[tid] = fmaxf(sred[tid], sred[tid + off]);
        __syncthreads();
    }
    float m = sred[0];
    __syncthreads();
    float ex[8];
    float lsum = 0.f;
    #pragma unroll
    for (int i = 0; i < 8; i++) {
        ex[i] = msk[i] ? 0.f : __expf(vals[i] - m);
        lsum += ex[i];
    }
    sred[tid] = lsum; __syncthreads();
    for (int off = 128; off > 0; off >>= 1) {
        if (tid < off) sred[tid] += sred[tid + off];
        __syncthreads();
    }
    float inv = 1.f / sred[0];
    #pragma unroll
    for (int i = 0; i < 8; i++) attn[b * SS + tid + i * 256] = ex[i] * inv;
}

// ---------------- ctx partials over s-chunks, masked-skip (no atomics) ----------
__global__ __launch_bounds__(256) void k_ctx_part(const float* __restrict__ enc,
                                                  const float* __restrict__ attn,
                                                  float* __restrict__ pctx) {
    const int b = blockIdx.x, z = blockIdx.y, tid = threadIdx.x;   // z: 0..31, 64 rows each
    float4 acc = {0.f, 0.f, 0.f, 0.f};
    const float4* e4 = (const float4*)(enc + ((size_t)b * SS + z * 64) * HE);
    const float*  ar = attn + b * SS + z * 64;
    for (int s = 0; s < 64; s++) {
        float a = ar[s];
        if (a != 0.f) {   // masked tokens have exactly-zero attn -> skip row read
            float4 v = e4[(size_t)s * 256 + tid];
            acc.x += a * v.x; acc.y += a * v.y; acc.z += a * v.z; acc.w += a * v.w;
        }
    }
    *(float4*)(pctx + ((size_t)z * 32 + b) * 1024 + tid * 4) = acc;
}

__global__ __launch_bounds__(256) void k_ctx_red(const float* __restrict__ pctx,
                                                 float* __restrict__ ctx) {
    int i = blockIdx.x * 256 + threadIdx.x;   // 0..32767
    float s = 0.f;
    #pragma unroll
    for (int z = 0; z < 32; z++) s += pctx[z * 32768 + i];
    ctx[i] = s;
}

// ================= fp32 fallback (round-0 proven path) =================
__global__ __launch_bounds__(256) void k_scores_f32(const float* __restrict__ enc,
                                                    const float* __restrict__ W,
                                                    const float* __restrict__ V,
                                                    const float* __restrict__ proj,
                                                    float* __restrict__ scores) {
    __shared__ float As[64][20];
    __shared__ float Bs[64][20];
    __shared__ float red[64][17];
    const int t0 = blockIdx.x * 64;
    const int b  = t0 >> 11;
    const int tid = threadIdx.x;
    const int tx = tid & 15, ty = tid >> 4;
    const int lrow = tid >> 2, lc4 = (tid & 3) * 4;
    float sc[4] = {0.f, 0.f, 0.f, 0.f};
    for (int n0 = 0; n0 < HD; n0 += 64) {
        float C[4][4] = {};
        for (int k0 = 0; k0 < HE; k0 += 16) {
            *(float4*)&As[lrow][lc4] = *(const float4*)(enc + (size_t)(t0 + lrow) * HE + k0 + lc4);
            *(float4*)&Bs[lrow][lc4] = *(const float4*)(W + (size_t)(n0 + lrow) * WROW + k0 + lc4);
            __syncthreads();
            #pragma unroll
            for (int k4 = 0; k4 < 16; k4 += 4) {
                float4 a[4], bb[4];
                #pragma unroll
                for (int i = 0; i < 4; i++) a[i]  = *(float4*)&As[ty * 4 + i][k4];
                #pragma unroll
                for (int j = 0; j < 4; j++) bb[j] = *(float4*)&Bs[tx * 4 + j][k4];
                #pragma unroll
                for (int i = 0; i < 4; i++)
                    #pragma unroll
                    for (int j = 0; j < 4; j++)
                        C[i][j] += a[i].x * bb[j].x + a[i].y * bb[j].y +
                                   a[i].z * bb[j].z + a[i].w * bb[j].w;
            }
            __syncthreads();
        }
        #pragma unroll
        for (int j = 0; j < 4; j++) {
            int d = n0 + tx * 4 + j;
            float pd = proj[b * HD + d];
            float v  = V[d];
            #pragma unroll
            for (int i = 0; i < 4; i++) {
                float y  = C[i][j] + pd;
                float e2 = __expf(2.f * y);
                sc[i] += v * (1.f - 2.f / (e2 + 1.f));
            }
        }
    }
    #pragma unroll
    for (int i = 0; i < 4; i++) red[ty * 4 + i][tx] = sc[i];
    __syncthreads();
    if (tid < 64) {
        float s = 0.f;
        #pragma unroll
        for (int x = 0; x < 16; x++) s += red[tid][x];
        scores[t0 + tid] = s;
    }
}

__global__ __launch_bounds__(256) void k_softmax_f32(float* __restrict__ sc_attn,
                                                     const int* __restrict__ mask) {
    __shared__ float sred[256];
    const int b = blockIdx.x, tid = threadIdx.x;
    float vals[8]; int msk[8];
    float lmax = -1e30f;
    #pragma unroll
    for (int i = 0; i < 8; i++) {
        int s = tid + i * 256;
        vals[i] = sc_attn[b * SS + s];
        msk[i]  = mask[b * SS + s];
        if (!msk[i]) lmax = fmaxf(lmax, vals[i]);
    }
    sred[tid] = lmax; __syncthreads();
    for (int off = 128; off > 0; off >>= 1) {
        if (tid < off) sred[tid] = fmaxf(sred[tid], sred[tid + off]);
        __syncthreads();
    }
    float m = sred[0];
    __syncthreads();
    float ex[8]; float lsum = 0.f;
    #pragma unroll
    for (int i = 0; i < 8; i++) { ex[i] = msk[i] ? 0.f : __expf(vals[i] - m); lsum += ex[i]; }
    sred[tid] = lsum; __syncthreads();
    for (int off = 128; off > 0; off >>= 1) {
        if (tid < off) sred[tid] += sred[tid + off];
        __syncthreads();
    }
    float inv = 1.f / sred[0];
    #pragma unroll
    for (int i = 0; i < 8; i++) sc_attn[b * SS + tid + i * 256] = ex[i] * inv;
}

__global__ __launch_bounds__(256) void k_ctx_atomic(const float* __restrict__ enc,
                                                    const float* __restrict__ attn,
                                                    float* __restrict__ ctx) {
    const int b = blockIdx.x;
    const int e = blockIdx.y * 256 + threadIdx.x;
    const int s0 = blockIdx.z * 256;
    float sum = 0.f;
    for (int s = s0; s < s0 + 256; s++)
        sum += attn[b * SS + s] * enc[((size_t)b * SS + s) * HE + e];
    atomicAdd(&ctx[b * HE + e], sum);
}

extern "C" void kernel_launch(void* const* d_in, const int* in_sizes, int n_in,
                              void* d_out, int out_size, void* d_ws, size_t ws_size,
                              hipStream_t stream) {
    const float* enc  = (const float*)d_in[0];
    const float* dec  = (const float*)d_in[1];
    const int*   mask = (const int*)d_in[2];
    const float* W    = (const float*)d_in[3];
    const float* V    = (const float*)d_in[4];

    float* out  = (float*)d_out;
    float* ctx  = out;               // [32][1024]
    float* attn = out + BB * HE;     // [32][2048]

    // ws layout (bytes): wf 2 MiB | proj 128 KiB | psc 1 MiB | pctx 4 MiB
    const size_t WF_OFF = 0, PROJ_OFF = 2097152, PSC_OFF = PROJ_OFF + 131072,
                 PCTX_OFF = PSC_OFF + 1048576, WS_NEED = PCTX_OFF + 4194304;
    if (ws_size >= WS_NEED) {
        char* w = (char*)d_ws;
        unsigned short* wf = (unsigned short*)(w + WF_OFF);
        float* proj        = (float*)(w + PROJ_OFF);
        float* psc         = (float*)(w + PSC_OFF);
        float* pctx        = (float*)(w + PCTX_OFF);

        k_cvt_wfrag<<<512, 256, 0, stream>>>(W, wf);
        k_projdec2<<<256, 256, 0, stream>>>(dec, W, proj);
        k_scores_mfma8b<<<1024, 512, 0, stream>>>(enc, wf, V, proj, psc);
        k_softmax_p<<<BB, 256, 0, stream>>>(psc, mask, attn);
        k_ctx_part<<<dim3(BB, 32), 256, 0, stream>>>(enc, attn, pctx);
        k_ctx_red<<<128, 256, 0, stream>>>(pctx, ctx);
    } else {
        float* proj  = ctx;
        float* score = attn;
        k_projdec2<<<256, 256, 0, stream>>>(dec, W, proj);
        k_scores_f32<<<(BB * SS) / 64, 256, 0, stream>>>(enc, W, V, proj, score);
        k_softmax_f32<<<BB, 256, 0, stream>>>(score, mask);
        hipMemsetAsync(ctx, 0, (size_t)BB * HE * sizeof(float), stream);
        k_ctx_atomic<<<dim3(BB, HE / 256, 8), 256, 0, stream>>>(enc, attn, ctx);
    }
}

// Round 2
// 204.733 us; speedup vs baseline: 1.1639x; 1.1639x over previous
//
#include <hip/hip_runtime.h>
#include <hip/hip_bf16.h>
#include <math.h>

#define BB 32
#define SS 2048
#define HE 1024
#define HD 1024
#define WROW (HE + HD)   // 2048

typedef __attribute__((ext_vector_type(8))) short bf16x8;
typedef __attribute__((ext_vector_type(4))) float f32x4;
typedef __attribute__((ext_vector_type(8))) unsigned short u16x8;

__device__ __forceinline__ unsigned short f2bf(float f) {
    union { float f; unsigned u; } v; v.f = f;
    unsigned r = v.u + 0x7fffu + ((v.u >> 16) & 1u);   // RNE
    return (unsigned short)(r >> 16);
}

__device__ __forceinline__ unsigned int pk2(float x, float y) {
    union { __hip_bfloat162 h; unsigned int u; } c;
    c.h = __float22bfloat162_rn(float2{x, y});          // v_cvt_pk_bf16_f32
    return c.u;
}

#define LGKM0()  asm volatile("s_waitcnt lgkmcnt(0)" ::: "memory")
#define BAR()    asm volatile("s_barrier" ::: "memory")

// ---------------- cvt: W_enc fp32 -> bf16 fragment-major ----------------
// Record (g, ksg): 64 lanes x 16B; lane l = W[d=g*16+(l&15)][k=ksg*32+(l>>4)*8 ..+8]
// g = d>>4 (0..63), ksg = k>>5 (0..31). One wave's bg load = 1KB contiguous.
__global__ __launch_bounds__(256) void k_cvt_wfrag(const float* __restrict__ W,
                                                   unsigned short* __restrict__ wf) {
    int i = blockIdx.x * 256 + threadIdx.x;   // 0..131071 (8-elem chunks)
    int d = i >> 7;                            // 0..1023
    int c = i & 127;                           // k-chunk: k = c*8
    const float4* src = (const float4*)(W + (size_t)d * WROW + c * 8);
    float4 a = src[0], b2 = src[1];
    u16x8 o;
    o[0] = f2bf(a.x);  o[1] = f2bf(a.y);  o[2] = f2bf(a.z);  o[3] = f2bf(a.w);
    o[4] = f2bf(b2.x); o[5] = f2bf(b2.y); o[6] = f2bf(b2.z); o[7] = f2bf(b2.w);
    int ksg = c >> 2, hi = c & 3;
    int l   = (d & 15) + 16 * hi;
    int g   = d >> 4;
    *(u16x8*)(wf + ((size_t)(g * 32 + ksg) * 64 + l) * 8) = o;
}

// ---------------- proj_dec: W_dec read ONCE total ----------------
__global__ __launch_bounds__(256) void k_projdec2(const float* __restrict__ dec,
                                                  const float* __restrict__ W,
                                                  float* __restrict__ proj) {
    const int tid = threadIdx.x;
    const int dl = tid >> 6;
    const int b  = (tid >> 1) & 31;
    const int hf = tid & 1;
    const int d  = blockIdx.x * 4 + dl;
    const float* wrow = W + (size_t)d * WROW + HE + hf * 512;
    const float* dv   = dec + b * HD + hf * 512;
    float s = 0.f;
    #pragma unroll 4
    for (int e = 0; e < 512; e += 4) {
        float4 w4 = *(const float4*)(wrow + e);
        float4 x4 = *(const float4*)(dv + e);
        s += w4.x * x4.x + w4.y * x4.y + w4.z * x4.z + w4.w * x4.w;
    }
    s += __shfl_xor(s, 1, 64);
    if (hf == 0) proj[b * HD + d] = s;
}

// ---------------- 8-wave 64x1024 MFMA scores; B direct global->reg ----------------
// R2 retile: block = 64 tokens x FULL d=1024 (was 256x256). A (enc) is loaded,
// converted and LDS-staged ONCE per element (was 4x, nb-redundant). Wave wv owns
// d in [wv*128, wv*128+128): 1M x 8N wave-tile 64x128, acc[4][8] = 128 AGPR.
// A: reg-staged fp32->bf16 -> XOR-swizzled LDS dbuf [2][64x64] = 16 KB.
// B: fragment-major global loads straight to VGPR (L2-resident 2MB wf), 16
//    dwordx4/wave/K-tile, reloaded consume-then-reload ~1 K-tile ahead; compiler
//    emits counted vmcnt. R0's proven single-barrier-per-K-tile schedule.
// Epilogue: full d-reduction in-block -> FINAL scores (no nb partials).
__global__ __launch_bounds__(512, 2) void k_scores_mfma8b(
        const float* __restrict__ enc,             // [65536][1024] fp32
        const unsigned short* __restrict__ wf,     // fragment-major bf16 W_enc
        const float* __restrict__ V,
        const float* __restrict__ proj,            // [32][1024]
        float* __restrict__ psc) {                 // [65536] final scores
    __shared__ unsigned short SM[16384];           // 32 KB: A dbuf 2x8KB; epilogue red 32KB

    const int tid = threadIdx.x;
    const int wv = tid >> 6, ln = tid & 63, l15 = ln & 15, lg = ln >> 4;

    // T1: bijective XCD swizzle over 1024 blocks; each XCD gets a contiguous
    // 128-tile (8192-token) chunk of enc for L3/L2 locality.
    const int lid  = (blockIdx.x & 7) * 128 + (blockIdx.x >> 3);
    const int t0   = lid * 64;
    const int b    = t0 >> 11;

    f32x4 acc[4][8];
    #pragma unroll
    for (int m = 0; m < 4; m++)
        #pragma unroll
        for (int n = 0; n < 8; n++) acc[m][n] = (f32x4){0.f, 0.f, 0.f, 0.f};

    float4 areg[2];                     // one K-tile of A: 64 rows x 64 k, 8 fp32/thread
    bf16x8 bgA[4], bgB[4], bgC[4], bgD[4];   // B frags: ks0 n0-3 / ks0 n4-7 / ks1 n0-3 / ks1 n4-7

    #define LOAD_A(k) do { \
        const float4* g_ = (const float4*)(enc + (size_t)(t0 + (tid >> 3)) * 1024 + (k) + (tid & 7) * 8); \
        areg[0] = g_[0]; areg[1] = g_[1]; \
    } while (0)

    #define CVTW_A(buf) do { \
        int row_ = tid >> 3; \
        union { u16x8 s; uint4 u; } pk_; \
        pk_.u.x = pk2(areg[0].x, areg[0].y); \
        pk_.u.y = pk2(areg[0].z, areg[0].w); \
        pk_.u.z = pk2(areg[1].x, areg[1].y); \
        pk_.u.w = pk2(areg[1].z, areg[1].w); \
        *(u16x8*)&SM[(buf) * 4096 + row_ * 64 + (((tid & 7) ^ (row_ & 7)) << 3)] = pk_.s; \
    } while (0)

    // bg fragment load: g = wv*8 + no + n, record (g*32 + t*2 + ksl), lane ln
    #define LOADB(bgx, tt, ksl, no) do { \
        _Pragma("unroll") \
        for (int n = 0; n < 4; n++) { \
            int g_ = wv * 8 + (no) + n; \
            bgx[n] = *(const bf16x8*)(wf + ((size_t)(g_ * 32 + (tt) * 2 + (ksl)) * 64 + ln) * 8); \
        } } while (0)

    #define RD_A(af, Ac, ks) do { \
        _Pragma("unroll") \
        for (int m = 0; m < 4; m++) { \
            int row_ = m * 16 + l15; \
            af[m] = *(const bf16x8*)&(Ac)[row_ * 64 + ((((ks) + lg) ^ (row_ & 7)) << 3)]; \
        } } while (0)

    #define MFMA4N(no, bg, af) do { \
        __builtin_amdgcn_s_setprio(1); \
        _Pragma("unroll") \
        for (int m = 0; m < 4; m++) \
            _Pragma("unroll") \
            for (int n = 0; n < 4; n++) \
                acc[m][(no) + n] = __builtin_amdgcn_mfma_f32_16x16x32_bf16(af[m], bg[n], acc[m][(no) + n], 0, 0, 0); \
        __builtin_amdgcn_s_setprio(0); } while (0)

    // ---- prologue: bg(0) all four quarters, A(0)->LDS, A(1) in flight ----
    LOADB(bgA, 0, 0, 0); LOADB(bgB, 0, 0, 4);
    LOADB(bgC, 0, 1, 0); LOADB(bgD, 0, 1, 4);
    LOAD_A(0);
    CVTW_A(0);                 // compiler waits A(0) loads, leaves bg in flight
    LOAD_A(64);                // A(1)
    LGKM0(); BAR();

    for (int t = 0; t < 16; ++t) {
        const int cur = t & 1, nxt = cur ^ 1;
        const unsigned short* Ac = SM + cur * 4096;
        bf16x8 af[4];

        // ks0: m0-3 x n0-7
        RD_A(af, Ac, 0);
        MFMA4N(0, bgA, af);
        MFMA4N(4, bgB, af);

        // slot: bgA/bgB dead -> reload for t+1; convert A(t+1)->LDS nxt; issue A(t+2)
        if (t < 15) {
            LOADB(bgA, t + 1, 0, 0);
            LOADB(bgB, t + 1, 0, 4);
            CVTW_A(nxt);                       // counted vmcnt on areg only
            if (t < 14) LOAD_A((t + 2) * 64);
        }

        // ks1: m0-3 x n0-7
        RD_A(af, Ac, 4);
        MFMA4N(0, bgC, af);
        MFMA4N(4, bgD, af);

        if (t < 15) {
            LOADB(bgC, t + 1, 1, 0);
            LOADB(bgD, t + 1, 1, 4);
            LGKM0(); BAR();                    // A dbuf coherence; B stays in flight
        }
    }
    #undef LOAD_A
    #undef CVTW_A
    #undef LOADB
    #undef RD_A
    #undef MFMA4N

    // ---- fused epilogue: sc[m][j] = sum_n V[d]*tanh(acc + proj), d = wv*128.. ----
    float sc[4][4];
    #pragma unroll
    for (int m = 0; m < 4; m++)
        #pragma unroll
        for (int j = 0; j < 4; j++) sc[m][j] = 0.f;
    #pragma unroll
    for (int n = 0; n < 8; n++) {
        int d = wv * 128 + n * 16 + l15;
        float pd  = proj[b * 1024 + d];
        float vv  = V[d];
        float vv2 = 2.f * vv;
        #pragma unroll
        for (int m = 0; m < 4; m++)
            #pragma unroll
            for (int j = 0; j < 4; j++) {
                float y  = acc[m][n][j] + pd;
                float e2 = __expf(2.f * y);                 // saturates at +/-inf
                float r  = __builtin_amdgcn_rcpf(e2 + 1.f);
                sc[m][j] += vv - vv2 * r;                   // vv * tanh(y)
            }
    }

    __syncthreads();           // all waves done with LDS; safe to alias
    float* red = (float*)SM;   // 64 tokens x 128 cols, rotated = 32KB (exact fit)
    #pragma unroll
    for (int m = 0; m < 4; m++)
        #pragma unroll
        for (int j = 0; j < 4; j++) {
            int tok = m * 16 + lg * 4 + j;
            int col = wv * 16 + l15;
            red[tok * 128 + ((col + tok) & 127)] = sc[m][j];
        }
    __syncthreads();
    if (tid < 64) {
        float s = 0.f;
        #pragma unroll
        for (int x = 0; x < 128; x++) s += red[tid * 128 + ((x + tid) & 127)];
        psc[t0 + tid] = s;
    }
}

// ---------------- masked softmax over S (final scores input) ----------------
__global__ __launch_bounds__(256) void k_softmax_p(const float* __restrict__ psc,
                                                   const int* __restrict__ mask,
                                                   float* __restrict__ attn) {
    __shared__ float sred[256];
    const int b = blockIdx.x, tid = threadIdx.x;
    float vals[8];
    int   msk[8];
    float lmax = -1e30f;
    #pragma unroll
    for (int i = 0; i < 8; i++) {
        int s = tid + i * 256;
        vals[i] = psc[b * SS + s];
        msk[i]  = mask[b * SS + s];
        if (!msk[i]) lmax = fmaxf(lmax, vals[i]);
    }
    sred[tid] = lmax; __syncthreads();
    for (int off = 128; off > 0; off >>= 1) {
        if (tid < off) sred[tid] = fmaxf(sred[tid], sred[tid + off]);
        __syncthreads();
    }
    float m = sred[0];
    __syncthreads();
    float ex[8];
    float lsum = 0.f;
    #pragma unroll
    for (int i = 0; i < 8; i++) {
        ex[i] = msk[i] ? 0.f : __expf(vals[i] - m);
        lsum += ex[i];
    }
    sred[tid] = lsum; __syncthreads();
    for (int off = 128; off > 0; off >>= 1) {
        if (tid < off) sred[tid] += sred[tid + off];
        __syncthreads();
    }
    float inv = 1.f / sred[0];
    #pragma unroll
    for (int i = 0; i < 8; i++) attn[b * SS + tid + i * 256] = ex[i] * inv;
}

// ---------------- ctx partials over s-chunks, masked-skip (no atomics) ----------
__global__ __launch_bounds__(256) void k_ctx_part(const float* __restrict__ enc,
                                                  const float* __restrict__ attn,
                                                  float* __restrict__ pctx) {
    const int b = blockIdx.x, z = blockIdx.y, tid = threadIdx.x;   // z: 0..31, 64 rows each
    float4 acc = {0.f, 0.f, 0.f, 0.f};
    const float4* e4 = (const float4*)(enc + ((size_t)b * SS + z * 64) * HE);
    const float*  ar = attn + b * SS + z * 64;
    for (int s = 0; s < 64; s++) {
        float a = ar[s];
        if (a != 0.f) {   // masked tokens have exactly-zero attn -> skip row read
            float4 v = e4[(size_t)s * 256 + tid];
            acc.x += a * v.x; acc.y += a * v.y; acc.z += a * v.z; acc.w += a * v.w;
        }
    }
    *(float4*)(pctx + ((size_t)z * 32 + b) * 1024 + tid * 4) = acc;
}

__global__ __launch_bounds__(256) void k_ctx_red(const float* __restrict__ pctx,
                                                 float* __restrict__ ctx) {
    int i = blockIdx.x * 256 + threadIdx.x;   // 0..32767
    float s = 0.f;
    #pragma unroll
    for (int z = 0; z < 32; z++) s += pctx[z * 32768 + i];
    ctx[i] = s;
}

// ================= fp32 fallback (round-0 proven path) =================
__global__ __launch_bounds__(256) void k_scores_f32(const float* __restrict__ enc,
                                                    const float* __restrict__ W,
                                                    const float* __restrict__ V,
                                                    const float* __restrict__ proj,
                                                    float* __restrict__ scores) {
    __shared__ float As[64][20];
    __shared__ float Bs[64][20];
    __shared__ float red[64][17];
    const int t0 = blockIdx.x * 64;
    const int b  = t0 >> 11;
    const int tid = threadIdx.x;
    const int tx = tid & 15, ty = tid >> 4;
    const int lrow = tid >> 2, lc4 = (tid & 3) * 4;
    float sc[4] = {0.f, 0.f, 0.f, 0.f};
    for (int n0 = 0; n0 < HD; n0 += 64) {
        float C[4][4] = {};
        for (int k0 = 0; k0 < HE; k0 += 16) {
            *(float4*)&As[lrow][lc4] = *(const float4*)(enc + (size_t)(t0 + lrow) * HE + k0 + lc4);
            *(float4*)&Bs[lrow][lc4] = *(const float4*)(W + (size_t)(n0 + lrow) * WROW + k0 + lc4);
            __syncthreads();
            #pragma unroll
            for (int k4 = 0; k4 < 16; k4 += 4) {
                float4 a[4], bb[4];
                #pragma unroll
                for (int i = 0; i < 4; i++) a[i]  = *(float4*)&As[ty * 4 + i][k4];
                #pragma unroll
                for (int j = 0; j < 4; j++) bb[j] = *(float4*)&Bs[tx * 4 + j][k4];
                #pragma unroll
                for (int i = 0; i < 4; i++)
                    #pragma unroll
                    for (int j = 0; j < 4; j++)
                        C[i][j] += a[i].x * bb[j].x + a[i].y * bb[j].y +
                                   a[i].z * bb[j].z + a[i].w * bb[j].w;
            }
            __syncthreads();
        }
        #pragma unroll
        for (int j = 0; j < 4; j++) {
            int d = n0 + tx * 4 + j;
            float pd = proj[b * HD + d];
            float v  = V[d];
            #pragma unroll
            for (int i = 0; i < 4; i++) {
                float y  = C[i][j] + pd;
                float e2 = __expf(2.f * y);
                sc[i] += v * (1.f - 2.f / (e2 + 1.f));
            }
        }
    }
    #pragma unroll
    for (int i = 0; i < 4; i++) red[ty * 4 + i][tx] = sc[i];
    __syncthreads();
    if (tid < 64) {
        float s = 0.f;
        #pragma unroll
        for (int x = 0; x < 16; x++) s += red[tid][x];
        scores[t0 + tid] = s;
    }
}

__global__ __launch_bounds__(256) void k_softmax_f32(float* __restrict__ sc_attn,
                                                     const int* __restrict__ mask) {
    __shared__ float sred[256];
    const int b = blockIdx.x, tid = threadIdx.x;
    float vals[8]; int msk[8];
    float lmax = -1e30f;
    #pragma unroll
    for (int i = 0; i < 8; i++) {
        int s = tid + i * 256;
        vals[i] = sc_attn[b * SS + s];
        msk[i]  = mask[b * SS + s];
        if (!msk[i]) lmax = fmaxf(lmax, vals[i]);
    }
    sred[tid] = lmax; __syncthreads();
    for (int off = 128; off > 0; off >>= 1) {
        if (tid < off) sred[tid] = fmaxf(sred[tid], sred[tid + off]);
        __syncthreads();
    }
    float m = sred[0];
    __syncthreads();
    float ex[8]; float lsum = 0.f;
    #pragma unroll
    for (int i = 0; i < 8; i++) { ex[i] = msk[i] ? 0.f : __expf(vals[i] - m); lsum += ex[i]; }
    sred[tid] = lsum; __syncthreads();
    for (int off = 128; off > 0; off >>= 1) {
        if (tid < off) sred[tid] += sred[tid + off];
        __syncthreads();
    }
    float inv = 1.f / sred[0];
    #pragma unroll
    for (int i = 0; i < 8; i++) sc_attn[b * SS + tid + i * 256] = ex[i] * inv;
}

__global__ __launch_bounds__(256) void k_ctx_atomic(const float* __restrict__ enc,
                                                    const float* __restrict__ attn,
                                                    float* __restrict__ ctx) {
    const int b = blockIdx.x;
    const int e = blockIdx.y * 256 + threadIdx.x;
    const int s0 = blockIdx.z * 256;
    float sum = 0.f;
    for (int s = s0; s < s0 + 256; s++)
        sum += attn[b * SS + s] * enc[((size_t)b * SS + s) * HE + e];
    atomicAdd(&ctx[b * HE + e], sum);
}

extern "C" void kernel_launch(void* const* d_in, const int* in_sizes, int n_in,
                              void* d_out, int out_size, void* d_ws, size_t ws_size,
                              hipStream_t stream) {
    const float* enc  = (const float*)d_in[0];
    const float* dec  = (const float*)d_in[1];
    const int*   mask = (const int*)d_in[2];
    const float* W    = (const float*)d_in[3];
    const float* V    = (const float*)d_in[4];

    float* out  = (float*)d_out;
    float* ctx  = out;               // [32][1024]
    float* attn = out + BB * HE;     // [32][2048]

    // ws layout (bytes): wf 2 MiB | proj 128 KiB | psc 1 MiB | pctx 4 MiB
    const size_t WF_OFF = 0, PROJ_OFF = 2097152, PSC_OFF = PROJ_OFF + 131072,
                 PCTX_OFF = PSC_OFF + 1048576, WS_NEED = PCTX_OFF + 4194304;
    if (ws_size >= WS_NEED) {
        char* w = (char*)d_ws;
        unsigned short* wf = (unsigned short*)(w + WF_OFF);
        float* proj        = (float*)(w + PROJ_OFF);
        float* psc         = (float*)(w + PSC_OFF);
        float* pctx        = (float*)(w + PCTX_OFF);

        k_cvt_wfrag<<<512, 256, 0, stream>>>(W, wf);
        k_projdec2<<<256, 256, 0, stream>>>(dec, W, proj);
        k_scores_mfma8b<<<1024, 512, 0, stream>>>(enc, wf, V, proj, psc);
        k_softmax_p<<<BB, 256, 0, stream>>>(psc, mask, attn);
        k_ctx_part<<<dim3(BB, 32), 256, 0, stream>>>(enc, attn, pctx);
        k_ctx_red<<<128, 256, 0, stream>>>(pctx, ctx);
    } else {
        float* proj  = ctx;
        float* score = attn;
        k_projdec2<<<256, 256, 0, stream>>>(dec, W, proj);
        k_scores_f32<<<(BB * SS) / 64, 256, 0, stream>>>(enc, W, V, proj, score);
        k_softmax_f32<<<BB, 256, 0, stream>>>(score, mask);
        hipMemsetAsync(ctx, 0, (size_t)BB * HE * sizeof(float), stream);
        k_ctx_atomic<<<dim3(BB, HE / 256, 8), 256, 0, stream>>>(enc, attn, ctx);
    }
}